// Round 1
// baseline (12337.315 us; speedup 1.0000x reference)
//
#include <hip/hip_runtime.h>
#include <hip/hip_bf16.h>

#define B_  64
#define S_  1024
#define I_  512
#define H_  512
#define G4  2048   // 4*H
#define KTOT 1024  // I_ + H_

typedef float f32x4 __attribute__((ext_vector_type(4)));
typedef short s16x8 __attribute__((ext_vector_type(8)));

__device__ inline ushort f2bf(float f) {
    union { __hip_bfloat16 h; ushort u; } v;
    v.h = __float2bfloat16(f);
    return v.u;
}

// WUt[g][k] = (k<512 ? W[k][g] : U[k-512][g]) as bf16.  [2048][1024]
__global__ __launch_bounds__(1024) void prep_wut(const float* __restrict__ W,
                                                 const float* __restrict__ U,
                                                 ushort* __restrict__ WUt) {
    __shared__ ushort lds[32][33];
    int g0 = blockIdx.x * 32, k0 = blockIdx.y * 32;
    int tx = threadIdx.x, ty = threadIdx.y;
    int k = k0 + ty, g = g0 + tx;
    float v = (k < I_) ? W[(size_t)k * G4 + g] : U[(size_t)(k - I_) * G4 + g];
    lds[ty][tx] = f2bf(v);
    __syncthreads();
    WUt[(size_t)(g0 + ty) * KTOT + k0 + tx] = lds[tx][ty];
}

__global__ __launch_bounds__(256) void init_state(ushort* __restrict__ h0,
                                                  float* __restrict__ c) {
    int i = blockIdx.x * 256 + threadIdx.x;   // 32768 total
    h0[i] = 0;
    c[i] = 0.0f;
}

// One timestep. Grid (32 jb, 4 bb), 256 threads = 4 waves (one per gate).
// Block owns batch rows [bb*16,+16) and hidden cols [jb*16,+16): computes the
// 4 gate tiles, then does the c/h update block-locally.
__global__ __launch_bounds__(256) void lstm_step(
    const float* __restrict__ x, const float* __restrict__ bias,
    const ushort* __restrict__ WUt, const ushort* __restrict__ h_prev,
    ushort* __restrict__ h_next, float* __restrict__ c,
    float* __restrict__ out, int t)
{
    __shared__ float glds[4][16][17];
    int jb = blockIdx.x, bb = blockIdx.y;
    int tid = threadIdx.x;
    int w = tid >> 6, lane = tid & 63;
    int m = lane & 15, q = lane >> 4;     // A-frag: row m, k = q*8+j
    int b = bb * 16 + m;

    const float*  xrow = x + ((size_t)b * S_ + t) * I_;       // x[b][t][*]
    const ushort* hrow = h_prev + b * H_;
    const ushort* brow = WUt + (size_t)(w * H_ + jb * 16 + m) * KTOT; // n = lane&15

    f32x4 acc = {0.f, 0.f, 0.f, 0.f};
    // K part 1: x_t @ W  (fp32 load + convert)
    #pragma unroll
    for (int kk = 0; kk < 16; ++kk) {
        int k0 = kk * 32 + q * 8;
        float4 xa = *(const float4*)(xrow + k0);
        float4 xb = *(const float4*)(xrow + k0 + 4);
        s16x8 a;
        a[0] = (short)f2bf(xa.x); a[1] = (short)f2bf(xa.y);
        a[2] = (short)f2bf(xa.z); a[3] = (short)f2bf(xa.w);
        a[4] = (short)f2bf(xb.x); a[5] = (short)f2bf(xb.y);
        a[6] = (short)f2bf(xb.z); a[7] = (short)f2bf(xb.w);
        s16x8 bv = *(const s16x8*)(brow + k0);
        acc = __builtin_amdgcn_mfma_f32_16x16x32_bf16(a, bv, acc, 0, 0, 0);
    }
    // K part 2: h @ U  (bf16 direct)
    #pragma unroll
    for (int kk = 0; kk < 16; ++kk) {
        int k0 = kk * 32 + q * 8;
        s16x8 a  = *(const s16x8*)(hrow + k0);
        s16x8 bv = *(const s16x8*)(brow + I_ + k0);
        acc = __builtin_amdgcn_mfma_f32_16x16x32_bf16(a, bv, acc, 0, 0, 0);
    }

    // C/D layout: col = lane&15 (hidden j), row = q*4+r (batch)
    #pragma unroll
    for (int r = 0; r < 4; ++r) glds[w][q * 4 + r][m] = acc[r];
    __syncthreads();

    int bl = tid >> 4, jl = tid & 15;
    int j  = jb * 16 + jl;
    int bg = bb * 16 + bl;
    float gi = glds[0][bl][jl] + bias[j];
    float gf = glds[1][bl][jl] + bias[H_ + j];
    float gg = glds[2][bl][jl] + bias[2 * H_ + j];
    float go = glds[3][bl][jl] + bias[3 * H_ + j];
    float iv = 1.f / (1.f + __expf(-gi));
    float fv = 1.f / (1.f + __expf(-gf));
    float gv = tanhf(gg);
    float ov = 1.f / (1.f + __expf(-go));
    int cidx = bg * H_ + j;
    float cv = fv * c[cidx] + iv * gv;
    c[cidx] = cv;
    float hv = ov * tanhf(cv);
    h_next[cidx] = f2bf(hv);
    out[((size_t)bg * S_ + t) * H_ + j] = hv;     // hidden_seq[b][t][j]
    if (t == S_ - 1) {
        out[(size_t)B_ * S_ * H_ + cidx] = hv;                  // h_t
        out[(size_t)B_ * S_ * H_ + (size_t)B_ * H_ + cidx] = cv; // c_t
    }
}

extern "C" void kernel_launch(void* const* d_in, const int* in_sizes, int n_in,
                              void* d_out, int out_size, void* d_ws, size_t ws_size,
                              hipStream_t stream) {
    const float* x    = (const float*)d_in[0];
    const float* W    = (const float*)d_in[1];
    const float* U    = (const float*)d_in[2];
    const float* bias = (const float*)d_in[3];
    float* out = (float*)d_out;
    char* ws = (char*)d_ws;

    // ws layout (~4.5 MiB total):
    ushort* WUt = (ushort*)ws;                               // 4 MiB
    ushort* h0  = (ushort*)(ws + 4 * 1024 * 1024);           // 64 KiB
    ushort* h1  = h0 + B_ * H_;                              // 64 KiB
    float*  c   = (float*)(ws + 4 * 1024 * 1024 + 2 * B_ * H_ * sizeof(ushort)); // 128 KiB

    prep_wut<<<dim3(G4 / 32, KTOT / 32), dim3(32, 32), 0, stream>>>(W, U, WUt);
    init_state<<<(B_ * H_) / 256, 256, 0, stream>>>(h0, c);

    ushort* hb[2] = {h0, h1};
    for (int t = 0; t < S_; ++t) {
        lstm_step<<<dim3(32, 4), 256, 0, stream>>>(
            x, bias, WUt, hb[t & 1], hb[(t + 1) & 1], c, out, t);
    }
}